// Round 3
// baseline (712.960 us; speedup 1.0000x reference)
//
#include <hip/hip_runtime.h>

// out[b] = sum_i x[b,i] * |W[i]| * fc1_w[i] + fc1_b ; B=32, N = 4e6.
// R2 finding: timed region = 2.048 GB poison-fill (~314 us) + restores + our
// kernels; three different stage1 access layouts timed identically -> theory:
// limiter is concurrent-DRAM-stream count (2048 blocks x 10 streams ~ 20K
// fronts thrashing HBM pages). This round: s=|W|*fc1_w staged in LDS once per
// chunk, then 32 row-passes with ONE x stream per block (512 streams chip-wide,
// 31KB bursts). W/F read from HBM exactly once. Total traffic 544 MB (floor).
#define BATCH 32
#define NELEM 4000000
#define N4 (NELEM / 4)                   // 1,000,000 f4 per batch row
#define BLK 256
#define NBLK 512                         // blocks: 2/CU, chunk contiguous
#define CHUNK ((N4 + NBLK - 1) / NBLK)   // 1954 f4 = 31.3 KB
#define WPB (BLK / 64)                   // 4 waves per block
#define PSTRIDE (NBLK * WPB)             // 2048 partials per batch row

typedef float f4 __attribute__((ext_vector_type(4)));

__global__ __launch_bounds__(BLK)
void stage1_kernel(const f4* __restrict__ x,       // [BATCH][N4]
                   const f4* __restrict__ W,       // [N4]
                   const f4* __restrict__ F,       // [N4]
                   float* __restrict__ partials) { // [BATCH][PSTRIDE]
    __shared__ f4 s_lds[CHUNK];                    // 31,264 B
    const int bx = blockIdx.x;
    const int t  = threadIdx.x;
    const int i0 = bx * CHUNK;
    const int len = (i0 + CHUNK <= N4) ? CHUNK : (N4 - i0);

    // Stage s = |W| * fc1_w for this chunk into LDS. W/F cross HBM once total.
    for (int i = t; i < len; i += BLK) {
        f4 wv = W[i0 + i];
        f4 fv = F[i0 + i];
        f4 s;
        s.x = fabsf(wv.x) * fv.x;
        s.y = fabsf(wv.y) * fv.y;
        s.z = fabsf(wv.z) * fv.z;
        s.w = fabsf(wv.w) * fv.w;
        s_lds[i] = s;
    }
    __syncthreads();

    const int lane = t & 63;
    const int wid  = t >> 6;

    // 32 passes, one batch row each: single x stream per block (31 KB burst).
    for (int r = 0; r < BATCH; ++r) {
        const f4* __restrict__ xr = x + (size_t)r * N4 + i0;
        float acc[4] = {0.f, 0.f, 0.f, 0.f};
        #pragma unroll
        for (int k = 0; k < 8; ++k) {              // 8*256 = 2048 >= CHUNK
            const int i = k * BLK + t;
            if (i < len) {
                f4 xv = __builtin_nontemporal_load(xr + i);   // pure stream
                f4 sv = s_lds[i];
                acc[k & 3] += xv.x * sv.x + xv.y * sv.y
                            + xv.z * sv.z + xv.w * sv.w;
            }
        }
        float a = (acc[0] + acc[1]) + (acc[2] + acc[3]);
        #pragma unroll
        for (int off = 32; off > 0; off >>= 1)
            a += __shfl_down(a, off, 64);
        if (lane == 0)
            partials[(size_t)r * PSTRIDE + bx * WPB + wid] = a;
    }
}

__global__ __launch_bounds__(64)
void stage2_kernel(const float* __restrict__ partials, // [BATCH][PSTRIDE]
                   const float* __restrict__ fc1_b,
                   float* __restrict__ out) {          // [BATCH]
    const int b    = blockIdx.x;   // 0..BATCH-1
    const int lane = threadIdx.x;  // 0..63
    float t = 0.0f;
    for (int k = lane; k < PSTRIDE; k += 64) t += partials[(size_t)b * PSTRIDE + k];
    #pragma unroll
    for (int off = 32; off > 0; off >>= 1) t += __shfl_down(t, off, 64);
    if (lane == 0) out[b] = t + fc1_b[0];
}

extern "C" void kernel_launch(void* const* d_in, const int* in_sizes, int n_in,
                              void* d_out, int out_size, void* d_ws, size_t ws_size,
                              hipStream_t stream) {
    const float* x     = (const float*)d_in[0];  // [B, T, P]
    const float* W     = (const float*)d_in[1];  // [T, P]
    const float* fc1_w = (const float*)d_in[2];  // [1, T*P]
    const float* fc1_b = (const float*)d_in[3];  // [1]
    float* out      = (float*)d_out;             // [B, 1]
    float* partials = (float*)d_ws;              // BATCH*PSTRIDE floats (256 KB)

    stage1_kernel<<<NBLK, BLK, 0, stream>>>(
        (const f4*)x, (const f4*)W, (const f4*)fc1_w, partials);
    stage2_kernel<<<BATCH, 64, 0, stream>>>(partials, fc1_b, out);
}

// Round 4
// 693.939 us; speedup vs baseline: 1.0274x; 1.0274x over previous
//
#include <hip/hip_runtime.h>

// out[b] = sum_i x[b,i] * |W[i]| * fc1_w[i] + fc1_b ; B=32, N = 4e6.
// R3 post-mortem: single-stream-per-block was right, paying 4x occupancy for
// it was wrong. This round: grid = (64 chunks x 32 rows) = 2048 blocks (8/CU,
// 32 waves/CU). Each block streams ONE contiguous 250 KB x-span (no 16MB-
// strided channel aliasing, which R1/R2 shared and timed identically), 12
// loads in flight. W/F re-read per row but same-chunk blocks share an XCD
// (linear%8 = c%8), so W/F comes from L2/L3 (32 MB fits L3); HBM ~= 544 MB.
#define BATCH 32
#define NELEM 4000000
#define N4 (NELEM / 4)          // 1,000,000 f4 per batch row
#define BLK 256
#define CHUNKS 64
#define CHUNK (N4 / CHUNKS)     // 15,625 f4 = 250 KB (exact: 64*15625 = 1e6)

typedef float f4 __attribute__((ext_vector_type(4)));

__device__ __forceinline__ float dot1(const f4* __restrict__ xr,
                                      const f4* __restrict__ W,
                                      const f4* __restrict__ F, int i) {
    f4 wv = W[i];                                   // L2/L3-hot
    f4 fv = F[i];
    f4 xv = __builtin_nontemporal_load(xr + i);     // pure HBM stream
    return xv.x * fabsf(wv.x) * fv.x + xv.y * fabsf(wv.y) * fv.y
         + xv.z * fabsf(wv.z) * fv.z + xv.w * fabsf(wv.w) * fv.w;
}

__global__ __launch_bounds__(BLK)
void stage1_kernel(const f4* __restrict__ x,       // [BATCH][N4]
                   const f4* __restrict__ W,       // [N4]
                   const f4* __restrict__ F,       // [N4]
                   float* __restrict__ partials) { // [BATCH][CHUNKS]
    const int c = blockIdx.x;                      // chunk 0..CHUNKS-1
    const int r = blockIdx.y;                      // batch row 0..BATCH-1
    const int t = threadIdx.x;
    const int i0 = c * CHUNK;
    const int i1 = i0 + CHUNK;
    const f4* __restrict__ xr = x + (size_t)r * N4;

    float a0 = 0.f, a1 = 0.f, a2 = 0.f, a3 = 0.f;
    int i = i0 + t;
    // 4x unroll: 12 independent 16B loads in flight per step.
    for (; i + 3 * BLK < i1; i += 4 * BLK) {
        a0 += dot1(xr, W, F, i);
        a1 += dot1(xr, W, F, i + BLK);
        a2 += dot1(xr, W, F, i + 2 * BLK);
        a3 += dot1(xr, W, F, i + 3 * BLK);
    }
    for (; i < i1; i += BLK)
        a0 += dot1(xr, W, F, i);

    float a = (a0 + a1) + (a2 + a3);
    #pragma unroll
    for (int off = 32; off > 0; off >>= 1)
        a += __shfl_down(a, off, 64);

    __shared__ float lds[BLK / 64];
    const int lane = t & 63;
    const int wid  = t >> 6;
    if (lane == 0) lds[wid] = a;
    __syncthreads();
    if (t == 0)
        partials[(size_t)r * CHUNKS + c] = lds[0] + lds[1] + lds[2] + lds[3];
}

__global__ __launch_bounds__(64)
void stage2_kernel(const float* __restrict__ partials, // [BATCH][CHUNKS]
                   const float* __restrict__ fc1_b,
                   float* __restrict__ out) {          // [BATCH]
    const int b    = blockIdx.x;   // 0..BATCH-1
    const int lane = threadIdx.x;  // 0..63  (CHUNKS == 64 exactly)
    float t = partials[(size_t)b * CHUNKS + lane];
    #pragma unroll
    for (int off = 32; off > 0; off >>= 1) t += __shfl_down(t, off, 64);
    if (lane == 0) out[b] = t + fc1_b[0];
}

extern "C" void kernel_launch(void* const* d_in, const int* in_sizes, int n_in,
                              void* d_out, int out_size, void* d_ws, size_t ws_size,
                              hipStream_t stream) {
    const float* x     = (const float*)d_in[0];  // [B, T, P]
    const float* W     = (const float*)d_in[1];  // [T, P]
    const float* fc1_w = (const float*)d_in[2];  // [1, T*P]
    const float* fc1_b = (const float*)d_in[3];  // [1]
    float* out      = (float*)d_out;             // [B, 1]
    float* partials = (float*)d_ws;              // BATCH*CHUNKS floats (8 KB)

    dim3 grid(CHUNKS, BATCH);
    stage1_kernel<<<grid, BLK, 0, stream>>>(
        (const f4*)x, (const f4*)W, (const f4*)fc1_w, partials);
    stage2_kernel<<<BATCH, 64, 0, stream>>>(partials, fc1_b, out);
}